// Round 6
// baseline (2487.300 us; speedup 1.0000x reference)
//
#include <hip/hip_runtime.h>
#include <stdint.h>

// Depthwise causal conv: y[b,c,p,q] = sum_{r<6,s<11} w[c,r,s]*xm[b,c,p+r-5,q+s-5]
// xm = x masked to lower triangle (h>=w); output masked to p>=q.
// N=2, C=16, H=W=2048.
// Structure = round-2 kernel (323us). ONE change: group-permuted LDS layout
// perm(g)=g^((g>>3)&1) so compute-phase ds_read_b128 hits every bank exactly
// once per 8 consecutive lanes (was {0,8,16,24} only -> 3.6e7 conflict cyc).

#define HDIM 2048
#define WDIM 2048
#define CH   16
#define RTAP 6
#define STAP 11

#define TH 32            // output tile rows per block
#define TW 128           // output tile cols per block
#define LDSR 37          // TH + 5 halo rows
#define GR   37          // 16B groups per LDS row: logical cols [q0-8, q0+140)
#define NSLOT (LDSR*GR)  // 1369 float4 slots = 21904 B -> 7 blocks/CU
#define NJ 6             // ceil(NSLOT/256)

// perm: involution on 0..36; spreads 32B-strided read lanes across banks.
#define PERM(g) ((g) ^ (((g) >> 3) & 1))

typedef const __attribute__((address_space(1))) uint32_t* gptr_t;
typedef __attribute__((address_space(3))) uint32_t* lptr_t;

__global__ __launch_bounds__(256, 7)
void dwconv_causal(const float* __restrict__ x, const float* __restrict__ wgt,
                   float* __restrict__ out) {
  const int bx = blockIdx.x, by = blockIdx.y, plane = blockIdx.z;
  const int q0 = bx * TW, p0 = by * TH;
  const int tid = threadIdx.x;
  const size_t pb = (size_t)plane * HDIM * WDIM;
  const float* __restrict__ xp = x + pb;
  float* __restrict__ op = out + pb;

  // Strictly-upper tile: zeros, no reads, no LDS.
  if (p0 + TH - 1 < q0) {
    const float4 z = make_float4(0.f, 0.f, 0.f, 0.f);
#pragma unroll
    for (int i = 0; i < 4; ++i) {  // 32 rows x 32 float4
      int idx = i * 256 + tid;
      int row = idx >> 5, c4 = idx & 31;
      *(float4*)(op + (size_t)(p0 + row) * WDIM + q0 + 4 * c4) = z;
    }
    return;
  }

  __shared__ __attribute__((aligned(16))) float lds[NSLOT * 4];

  // Weights: block-uniform address -> scalar loads into SGPRs.
  const float* __restrict__ wc = wgt + (plane & (CH - 1)) * (RTAP * STAP);
  float wr[RTAP * STAP];
#pragma unroll
  for (int i = 0; i < RTAP * STAP; ++i) wr[i] = wc[i];

  // Pure: every staged element in-bounds AND causal.
  // Staged rows [p0-5, p0+31]; cols [q0-8, q0+139].
  const bool pure = (bx >= 1) && (bx <= 14) && (p0 >= q0 + 144);

  if (pure) {
    // Async global->LDS: LINEAR dest (wave-uniform base + lane*16); the group
    // permutation is folded into the SOURCE address (both-sides rule).
#pragma unroll
    for (int j = 0; j < NJ; ++j) {
      int slot = j * 256 + tid;
      if (slot < NSLOT) {  // prefix-contiguous lanes -> base-lane rule OK
        int row = slot / GR;
        int pg = slot - row * GR;
        int g = PERM(pg);  // logical group stored at phys slot
        const float* ga = xp + (size_t)(p0 - 5 + row) * WDIM + (q0 - 8 + 4 * g);
        __builtin_amdgcn_global_load_lds((gptr_t)ga, (lptr_t)&lds[slot * 4],
                                         16, 0, 0);
      }
    }
  } else {
    // Edge/diagonal tile: reg roundtrip with causal + bounds predication.
#pragma unroll
    for (int j = 0; j < NJ; ++j) {
      int slot = j * 256 + tid;
      if (slot < NSLOT) {
        int row = slot / GR;
        int pg = slot - row * GR;
        int g = PERM(pg);
        int ih = p0 - 5 + row;
        int cb = q0 - 8 + 4 * g;
        float4 v = make_float4(0.f, 0.f, 0.f, 0.f);
        if (ih >= 0) {  // ih <= p0+31 <= 2047 always
          bool fullv = (cb >= 0) && (cb + 3 <= ih) && (cb + 3 < WDIM);
          if (fullv) {
            v = *(const float4*)(xp + (size_t)ih * WDIM + cb);
          } else {
            float* vv = &v.x;
#pragma unroll
            for (int e = 0; e < 4; ++e) {
              int iw = cb + e;
              if (iw >= 0 && iw < WDIM && iw <= ih)
                vv[e] = xp[(size_t)ih * WDIM + iw];
            }
          }
        }
        *(float4*)&lds[slot * 4] = v;
      }
    }
  }

  __syncthreads();

  // ---- Compute: 2 rows x 8 cols per thread (round-2 pattern) ----
  const int tx = tid & 15;   // col octet: cols q0+8tx .. +7
  const int ty = tid >> 4;   // rows p0+2ty, p0+2ty+1
  const int orow0 = ty * 2;

  float acc[2][8];
#pragma unroll
  for (int a = 0; a < 2; ++a)
#pragma unroll
    for (int b = 0; b < 8; ++b) acc[a][b] = 0.f;

#pragma unroll
  for (int ihl = 0; ihl < 7; ++ihl) {  // 7 LDS rows feed 2 output rows
    const int l = orow0 + ihl;
    float xrow[24];                    // logical cols [8tx-8, 8tx+16) rel q0
#pragma unroll
    for (int k = 0; k < 6; ++k) {
      int gl = 2 * tx + k;             // logical group
      int gs = PERM(gl);               // physical slot within row
      *(float4*)&xrow[4 * k] = *(const float4*)&lds[(l * GR + gs) * 4];
    }
#pragma unroll
    for (int ro = 0; ro < 2; ++ro) {
      if (ro < ihl - 5 || ro > ihl) continue;  // const after unroll
      const int rr = ihl - ro;                 // tap row 0..5
#pragma unroll
      for (int s = 0; s < STAP; ++s) {
        const float wv = wr[rr * STAP + s];
#pragma unroll
        for (int cc = 0; cc < 8; ++cc)
          acc[ro][cc] += wv * xrow[cc + s + 3];  // idx in [3,20]
      }
    }
  }

  // ---- Store with causal output mask (256B contiguous per 16 lanes) ----
  const int qb = q0 + 8 * tx;
  const bool fullcausal = (q0 + TW - 1 <= p0);
#pragma unroll
  for (int ro = 0; ro < 2; ++ro) {
    const int p = p0 + orow0 + ro;
    if (!fullcausal) {
#pragma unroll
      for (int cc = 0; cc < 8; ++cc)
        if (qb + cc > p) acc[ro][cc] = 0.f;
    }
    *(float4*)(op + (size_t)p * WDIM + qb) =
        make_float4(acc[ro][0], acc[ro][1], acc[ro][2], acc[ro][3]);
    *(float4*)(op + (size_t)p * WDIM + qb + 4) =
        make_float4(acc[ro][4], acc[ro][5], acc[ro][6], acc[ro][7]);
  }
}

extern "C" void kernel_launch(void* const* d_in, const int* in_sizes, int n_in,
                              void* d_out, int out_size, void* d_ws, size_t ws_size,
                              hipStream_t stream) {
  const float* x   = (const float*)d_in[0];
  const float* wgt = (const float*)d_in[1];
  float* out       = (float*)d_out;
  dim3 grid(WDIM / TW, HDIM / TH, 2 * CH);  // (16, 64, 32)
  dwconv_causal<<<grid, dim3(256), 0, stream>>>(x, wgt, out);
}

// Round 7
// 826.408 us; speedup vs baseline: 3.0098x; 3.0098x over previous
//
#include <hip/hip_runtime.h>
#include <stdint.h>

// Depthwise causal conv: y[b,c,p,q] = sum_{r<6,s<11} w[c,r,s]*xm[b,c,p+r-5,q+s-5]
// xm = x masked lower-triangular (h>=w); output masked p>=q. N=2,C=16,H=W=2048.
//
// Base = round-2 kernel (proven 323us, clean traffic). Changes:
//  (1) two 32-row tiles per block, double-buffered: stage A; sync; issue async
//      stage B; compute A; sync; compute B  -> stage-B HBM latency hides under
//      compute-A (plain __syncthreads only; global_load_lds is vmcnt-only so
//      compute-A's ds_read lgkm waits don't drain it).
//  (2) weights forced to SGPRs via readfirstlane (r6 spill-flip protection).

#define HDIM 2048
#define WDIM 2048
#define CH   16
#define RTAP 6
#define STAP 11

#define TH 32            // rows per sub-tile
#define TW 128           // cols per tile
#define LDSR 37          // TH + 5 halo rows
#define NGRP 36          // 16B groups per row: cols [q0-8, q0+136)
#define NSLOT (LDSR*NGRP)  // 1332 float4 slots = 21312 B per buffer
#define NJ 6             // ceil(NSLOT/256)

typedef const __attribute__((address_space(1))) uint32_t* gptr_t;
typedef __attribute__((address_space(3))) uint32_t* lptr_t;

__global__ __launch_bounds__(256, 3)
void dwconv_causal(const float* __restrict__ x, const float* __restrict__ wgt,
                   float* __restrict__ out) {
  const int bx = blockIdx.x, by = blockIdx.y, plane = blockIdx.z;
  const int q0 = bx * TW;
  const int p0A = by * (2 * TH);
  const int p0B = p0A + TH;
  const int tid = threadIdx.x;
  const int tx = tid & 15, ty = tid >> 4;
  const size_t pb = (size_t)plane * HDIM * WDIM;
  const float* __restrict__ xp = x + pb;
  float* __restrict__ op = out + pb;

  const bool upA = (p0A + TH - 1 < q0);
  const bool upB = (p0B + TH - 1 < q0);  // upB implies upA

  if (upB) {  // both sub-tiles strictly upper: zeros only
    const float4 z = make_float4(0.f, 0.f, 0.f, 0.f);
#pragma unroll
    for (int i = 0; i < 8; ++i) {  // 64 rows x 32 float4
      int idx = i * 256 + tid;
      int row = idx >> 5, c4 = idx & 31;
      *(float4*)(op + (size_t)(p0A + row) * WDIM + q0 + 4 * c4) = z;
    }
    return;
  }

  __shared__ __attribute__((aligned(16))) float lds[2][NSLOT * 4];  // 42.6 KB

  // Weights: wave-uniform -> force SGPR residency via readfirstlane.
  const float* __restrict__ wc = wgt + (plane & (CH - 1)) * (RTAP * STAP);
  float wr[RTAP * STAP];
#pragma unroll
  for (int i = 0; i < RTAP * STAP; ++i)
    wr[i] = __int_as_float(
        __builtin_amdgcn_readfirstlane(__float_as_int(wc[i])));

  // ---- staging (round-2 verbatim, parameterized by tile/buffer) ----
  auto stage = [&](int p0, float* buf) {
    // pure: staged rows [p0-5,p0+31], cols [q0-8,q0+135] all in-bounds+causal.
    // (bx=15 can't be pure: needs p0>=2060>2047 -> OOB right halo impossible.)
    const bool pure = (bx >= 1) && (q0 + 140 <= p0);
    if (pure) {
#pragma unroll
      for (int j = 0; j < NJ; ++j) {
        int slot = j * 256 + tid;
        if (slot < NSLOT) {  // prefix-contiguous lanes -> base-lane rule OK
          int row = slot / NGRP;
          int gp = slot - row * NGRP;
          int g = gp ^ ((row >> 1) & 1);  // bank swizzle (involution)
          const float* ga =
              xp + (size_t)(p0 - 5 + row) * WDIM + (q0 - 8 + 4 * g);
          __builtin_amdgcn_global_load_lds((gptr_t)ga, (lptr_t)(buf + slot * 4),
                                           16, 0, 0);
        }
      }
    } else {
#pragma unroll
      for (int j = 0; j < NJ; ++j) {
        int slot = j * 256 + tid;
        if (slot < NSLOT) {
          int row = slot / NGRP;
          int gp = slot - row * NGRP;
          int g = gp ^ ((row >> 1) & 1);
          int ih = p0 - 5 + row;
          int cb = q0 - 8 + 4 * g;
          float4 v = make_float4(0.f, 0.f, 0.f, 0.f);
          if (ih >= 0) {  // ih <= p0+31 <= 2047 always
            bool fullv = (cb >= 0) && (cb + 3 <= ih) && (cb + 3 < WDIM);
            if (fullv) {
              v = *(const float4*)(xp + (size_t)ih * WDIM + cb);
            } else {
              float* vv = &v.x;
#pragma unroll
              for (int e = 0; e < 4; ++e) {
                int iw = cb + e;
                if (iw >= 0 && iw < WDIM && iw <= ih)
                  vv[e] = xp[(size_t)ih * WDIM + iw];
              }
            }
          }
          *(float4*)(buf + slot * 4) = v;
        }
      }
    }
  };

  // ---- compute+store (round-2 verbatim, parameterized) ----
  auto computeTile = [&](int p0, const float* lb) {
    const int orow0 = ty * 2;
    float acc[2][8];
#pragma unroll
    for (int a = 0; a < 2; ++a)
#pragma unroll
      for (int b = 0; b < 8; ++b) acc[a][b] = 0.f;

#pragma unroll
    for (int ihl = 0; ihl < 7; ++ihl) {  // 7 LDS rows feed 2 output rows
      const int l = orow0 + ihl;
      const int xr = (l >> 1) & 1;
      float xrow[24];  // logical cols [8tx-8, 8tx+16) rel q0
#pragma unroll
      for (int k = 0; k < 6; ++k) {
        int gs = (tx * 2 + k) ^ xr;
        *(float4*)&xrow[4 * k] = *(const float4*)&lb[(l * NGRP + gs) * 4];
      }
#pragma unroll
      for (int ro = 0; ro < 2; ++ro) {
        if (ro < ihl - 5 || ro > ihl) continue;  // const after unroll
        const int rr = ihl - ro;                 // tap row 0..5
#pragma unroll
        for (int s = 0; s < STAP; ++s) {
          const float wv = wr[rr * STAP + s];
#pragma unroll
          for (int cc = 0; cc < 8; ++cc)
            acc[ro][cc] += wv * xrow[cc + s + 3];  // idx in [3,20]
        }
      }
    }

    const int qb = q0 + 8 * tx;
    const bool fullcausal = (q0 + TW - 1 <= p0);
#pragma unroll
    for (int ro = 0; ro < 2; ++ro) {
      const int p = p0 + orow0 + ro;
      if (!fullcausal) {
#pragma unroll
        for (int cc = 0; cc < 8; ++cc)
          if (qb + cc > p) acc[ro][cc] = 0.f;
      }
      *(float4*)(op + (size_t)p * WDIM + qb) =
          make_float4(acc[ro][0], acc[ro][1], acc[ro][2], acc[ro][3]);
      *(float4*)(op + (size_t)p * WDIM + qb + 4) =
          make_float4(acc[ro][4], acc[ro][5], acc[ro][6], acc[ro][7]);
    }
  };

  auto zeroTile = [&](int p0) {
    const float4 z = make_float4(0.f, 0.f, 0.f, 0.f);
#pragma unroll
    for (int i = 0; i < 4; ++i) {  // 32 rows x 32 float4
      int idx = i * 256 + tid;
      int row = idx >> 5, c4 = idx & 31;
      *(float4*)(op + (size_t)(p0 + row) * WDIM + q0 + 4 * c4) = z;
    }
  };

  // ---- pipeline: stageA | sync | stageB issue | computeA | sync | computeB
  if (!upA) stage(p0A, &lds[0][0]);
  __syncthreads();                 // drains A's loads
  stage(p0B, &lds[1][0]);          // B never strictly-upper here; its HBM
                                   // latency hides under compute/zero of A
  if (upA) zeroTile(p0A);
  else     computeTile(p0A, &lds[0][0]);
  __syncthreads();                 // drains B's loads
  computeTile(p0B, &lds[1][0]);
}

extern "C" void kernel_launch(void* const* d_in, const int* in_sizes, int n_in,
                              void* d_out, int out_size, void* d_ws, size_t ws_size,
                              hipStream_t stream) {
  const float* x   = (const float*)d_in[0];
  const float* wgt = (const float*)d_in[1];
  float* out       = (float*)d_out;
  dim3 grid(WDIM / TW, HDIM / (2 * TH), 2 * CH);  // (16, 32, 32)
  dwconv_causal<<<grid, dim3(256), 0, stream>>>(x, wgt, out);
}

// Round 8
// 299.790 us; speedup vs baseline: 8.2968x; 2.7566x over previous
//
#include <hip/hip_runtime.h>
#include <stdint.h>

// Depthwise causal conv via MFMA Toeplitz:
//   y[p, q0+16t+j] = sum_r sum_k x[p+r-5, q0+16t-8+k] * B_r[k,j],
//   B_r[k,j] = w[r, k-j-3] for k-j in [3,13], else 0.   (s = k-j-3 in [0,10])
// Precision: x staged as hi+lo bf16 pair (two MFMA chains) -> ~f32 accuracy.
// N=2, C=16, H=W=2048. Block = 4 waves = 64x64 outputs.

#define HDIM 2048
#define WDIM 2048
#define CH   16

#define PITCH 88          // LDS row pitch in shorts (176B): bank-uniform b128
#define XROWS 69          // 64 + 5 halo rows
#define XCOLS 80          // cols [q0-8, q0+72)
#define NSL   (XROWS * 20)  // staging slots (float4 granules): 1380

typedef float  f32x4  __attribute__((ext_vector_type(4)));
typedef short  bf16x8 __attribute__((ext_vector_type(8)));

static __device__ inline short f2bf(float f) {  // RNE f32 -> bf16 bits
  uint32_t u = __float_as_uint(f);
  return (short)((u + 0x7FFFu + ((u >> 16) & 1u)) >> 16);
}
static __device__ inline float bf2f(short h) {
  return __uint_as_float(((uint32_t)(uint16_t)h) << 16);
}

__global__ __launch_bounds__(256, 4)
void dwconv_mfma(const float* __restrict__ x, const float* __restrict__ wgt,
                 float* __restrict__ out) {
  const int bx = blockIdx.x, by = blockIdx.y, plane = blockIdx.z;
  const int q0 = bx * 64, p0 = by * 64;
  const int tid = threadIdx.x;
  const size_t pb = (size_t)plane * HDIM * WDIM;
  const float* __restrict__ xp = x + pb;
  float* __restrict__ op = out + pb;

  // Strictly-upper block: zeros only.
  if (p0 + 63 < q0) {
    const float4 z = make_float4(0.f, 0.f, 0.f, 0.f);
#pragma unroll
    for (int i = 0; i < 4; ++i) {  // 64 rows x 16 float4
      int idx = i * 256 + tid;
      int row = idx >> 4, c4 = idx & 15;
      *(float4*)(op + (size_t)(p0 + row) * WDIM + q0 + 4 * c4) = z;
    }
    return;
  }

  __shared__ short s_hi[XROWS * PITCH];  // 12144 B
  __shared__ short s_lo[XROWS * PITCH];  // 12144 B

  // ---- Stage x tile as bf16 hi/lo (causal + bounds mask folded in) ----
  // pure: rows [p0-5,p0+63], cols [q0-8,q0+71] all in-bounds AND causal
  // (max col q0+71 <= min row p0-5).
  const bool pure = (bx >= 1) && (bx <= 30) && (p0 >= q0 + 76);
#pragma unroll
  for (int j = 0; j < 6; ++j) {
    int slot = j * 256 + tid;
    if (slot < NSL) {
      int row = slot / 20;
      int c4 = slot - row * 20;
      int ih = p0 - 5 + row;
      int cb = q0 - 8 + 4 * c4;
      float4 v = make_float4(0.f, 0.f, 0.f, 0.f);
      if (pure) {
        v = *(const float4*)(xp + (size_t)ih * WDIM + cb);
      } else if (ih >= 0) {  // ih <= p0+63 <= 2047 always
        bool fullv = (cb >= 0) && (cb + 3 <= ih) && (cb + 3 < WDIM);
        if (fullv) {
          v = *(const float4*)(xp + (size_t)ih * WDIM + cb);
        } else {
          float* vv = &v.x;
#pragma unroll
          for (int e = 0; e < 4; ++e) {
            int iw = cb + e;
            if (iw >= 0 && iw < WDIM && iw <= ih)
              vv[e] = xp[(size_t)ih * WDIM + iw];
          }
        }
      }
      short4 h4, l4;
      h4.x = f2bf(v.x); l4.x = f2bf(v.x - bf2f(h4.x));
      h4.y = f2bf(v.y); l4.y = f2bf(v.y - bf2f(h4.y));
      h4.z = f2bf(v.z); l4.z = f2bf(v.z - bf2f(h4.z));
      h4.w = f2bf(v.w); l4.w = f2bf(v.w - bf2f(h4.w));
      int so = row * PITCH + 4 * c4;
      *(short4*)&s_hi[so] = h4;
      *(short4*)&s_lo[so] = l4;
    }
  }

  // ---- Build 6 Toeplitz B-fragments (one per tap row r) ----
  // B operand layout: lane holds B[k = 8*(lane>>4)+i, j = lane&15], i=0..7.
  const int lane = tid & 63;
  const int j16 = lane & 15;
  const int wk = lane >> 4;
  const float* __restrict__ wcp = wgt + (plane & (CH - 1)) * 66;
  bf16x8 bw[6];
#pragma unroll
  for (int r = 0; r < 6; ++r) {
#pragma unroll
    for (int i = 0; i < 8; ++i) {
      int k = 8 * wk + i;
      int d = k - j16 - 3;                    // = s tap index
      float wv = (d >= 0 && d <= 10) ? wcp[r * 11 + d] : 0.f;
      bw[r][i] = f2bf(wv);
    }
  }

  __syncthreads();

  // ---- 4 waves x (4 col-tiles x 6 r x 2 hi/lo) MFMAs ----
  const int wid = tid >> 6;  // wave's 16-row strip
  f32x4 acc[4];
#pragma unroll
  for (int t = 0; t < 4; ++t) acc[t] = (f32x4){0.f, 0.f, 0.f, 0.f};

#pragma unroll
  for (int t = 0; t < 4; ++t) {
#pragma unroll
    for (int r = 0; r < 6; ++r) {
      // A layout: lane holds A[m = lane&15, k = 8*(lane>>4)+i];
      // A[m,k] = x_tile[16*wid + m + r, 16t + k]  (LDS cols rel q0-8).
      int off = (16 * wid + j16 + r) * PITCH + 16 * t + 8 * wk;
      bf16x8 ah = *(const bf16x8*)&s_hi[off];
      bf16x8 al = *(const bf16x8*)&s_lo[off];
      acc[t] = __builtin_amdgcn_mfma_f32_16x16x32_bf16(ah, bw[r], acc[t], 0, 0, 0);
      acc[t] = __builtin_amdgcn_mfma_f32_16x16x32_bf16(al, bw[r], acc[t], 0, 0, 0);
    }
  }

  // ---- Store: D layout col = lane&15, row = 4*(lane>>4)+reg ----
  const bool needmask = (q0 + 63 > p0);
#pragma unroll
  for (int t = 0; t < 4; ++t) {
    const int q = q0 + 16 * t + j16;
#pragma unroll
    for (int reg = 0; reg < 4; ++reg) {
      const int p = p0 + 16 * wid + 4 * wk + reg;
      float val = acc[t][reg];
      if (needmask && q > p) val = 0.f;
      op[(size_t)p * WDIM + q] = val;
    }
  }
}

extern "C" void kernel_launch(void* const* d_in, const int* in_sizes, int n_in,
                              void* d_out, int out_size, void* d_ws, size_t ws_size,
                              hipStream_t stream) {
  const float* x   = (const float*)d_in[0];
  const float* wgt = (const float*)d_in[1];
  float* out       = (float*)d_out;
  dim3 grid(WDIM / 64, HDIM / 64, 2 * CH);  // (32, 32, 32)
  dwconv_mfma<<<grid, dim3(256), 0, stream>>>(x, wgt, out);
}